// Round 1
// baseline (322.485 us; speedup 1.0000x reference)
//
#include <hip/hip_runtime.h>
#include <hip/hip_bf16.h>
#include <math.h>

#define T_ 1024
#define H_ 1024
#define E_ 16
#define I_ 512
#define KSEL 4
#define IS_ 1024

typedef __attribute__((ext_vector_type(8))) short short8;
typedef __attribute__((ext_vector_type(4))) float f32x4;

__device__ __forceinline__ unsigned short f2bf(float f) {
    union { float f; unsigned int u; } v; v.f = f;
    unsigned int u = v.u;
    unsigned int r = (u + 0x7fffu + ((u >> 16) & 1u)) >> 16;
    return (unsigned short)r;
}
__device__ __forceinline__ float bf2f(unsigned short b) {
    union { unsigned int u; float f; } v; v.u = ((unsigned int)b) << 16;
    return v.f;
}

// ---------------- x -> bf16 ----------------
__global__ void convert_kernel(const float* __restrict__ in, unsigned short* __restrict__ out, int n4) {
    int i = blockIdx.x * blockDim.x + threadIdx.x;
    if (i >= n4) return;
    float4 v = ((const float4*)in)[i];
    ushort4 o;
    o.x = f2bf(v.x); o.y = f2bf(v.y); o.z = f2bf(v.z); o.w = f2bf(v.w);
    ((ushort4*)out)[i] = o;
}

// ---------------- router ----------------
__global__ __launch_bounds__(64)
void router_kernel(const float* __restrict__ x, const float* __restrict__ Wg,
                   const float* __restrict__ bias, int* __restrict__ counts,
                   int* __restrict__ tok_list, int* __restrict__ slot_list,
                   float* __restrict__ wt_list, int cap) {
    int t = blockIdx.x;
    int lane = threadIdx.x;
    float xr[16];
#pragma unroll
    for (int i = 0; i < 16; i++) xr[i] = x[t * H_ + i * 64 + lane];
    __shared__ float sc[E_];
    for (int e = 0; e < E_; e++) {
        const float* w = Wg + e * H_;
        float d = 0.f;
#pragma unroll
        for (int i = 0; i < 16; i++) d += xr[i] * w[i * 64 + lane];
#pragma unroll
        for (int off = 32; off; off >>= 1) d += __shfl_xor(d, off);
        if (lane == 0) sc[e] = d;
    }
    __syncthreads();
    if (lane == 0) {
        float score[E_], bsc[E_];
        bool taken[E_];
        for (int e = 0; e < E_; e++) {
            float lg = sc[e];
            float sp = fmaxf(lg, 0.f) + log1pf(expf(-fabsf(lg)));  // softplus, stable
            float s = sqrtf(sp);
            score[e] = s;
            bsc[e] = s + bias[e];
            taken[e] = false;
        }
        int sel[KSEL]; float wv[KSEL]; float wsum = 0.f;
        for (int k = 0; k < KSEL; k++) {
            float best = -1e30f; int bi = 0;
            for (int e = 0; e < E_; e++)
                if (!taken[e] && bsc[e] > best) { best = bsc[e]; bi = e; }
            taken[bi] = true; sel[k] = bi; wv[k] = score[bi]; wsum += score[bi];
        }
        float inv = 2.5f / wsum;
        for (int k = 0; k < KSEL; k++) {
            int e = sel[k];
            int pos = atomicAdd(&counts[e], 1);
            if (pos < cap) {
                tok_list[e * T_ + pos] = t;
                slot_list[e * T_ + pos] = t * KSEL + k;
                wt_list[e * T_ + pos] = wv[k] * inv;
            }
        }
    }
}

// ---------------- unified bf16 MFMA GEMM ----------------
// C[M,N] = A[M,K](bf16) * B[K,N](fp32, converted inline)
// EXPERT: blockIdx.z = expert, M limit = min(counts[e], cap)
// GATHER_A: A row indices from gather[e*T_+row]
// SCATTER_C: C row indices from scatter[e*T_+row]
template<bool EXPERT, bool GATHER_A, bool SCATTER_C, bool C_F32>
__global__ __launch_bounds__(256)
void gemm_kernel(const unsigned short* __restrict__ A, int lda, long sAe,
                 const float* __restrict__ B, int ldb, long sBe,
                 void* __restrict__ C, int ldc, long sCe,
                 int Mfull, int Ktot,
                 const int* __restrict__ counts, int cap,
                 const int* __restrict__ gather, const int* __restrict__ scatter) {
    int e = 0;
    int Mlim = Mfull;
    if (EXPERT) {
        e = blockIdx.z;
        int c = counts[e];
        Mlim = c < cap ? c : cap;
    }
    int mbase = blockIdx.y * 128;
    if (mbase >= Mlim) return;
    int nbase = blockIdx.x * 128;

    __shared__ __align__(16) unsigned short As[128 * 40];
    __shared__ __align__(16) unsigned short Bs[128 * 40];

    int tid = threadIdx.x;
    int lane = tid & 63, wid = tid >> 6;
    int wm = wid >> 1, wn = wid & 1;
    int lr = lane & 15, lk = lane >> 4;

    f32x4 acc[4][4] = {};

    // A staging assignment: thread -> (row, 16-elem half)
    int ar = tid >> 1;
    int ahf = (tid & 1) << 4;   // 0 or 16 (bf16 elems)
    int grow_a = mbase + ar;
    long arow = -1;
    if (grow_a < Mlim)
        arow = GATHER_A ? (long)gather[(long)e * T_ + grow_a] : (long)grow_a;
    const unsigned short* Ab = A + ((EXPERT && !GATHER_A) ? (long)e * sAe : 0L);
    const unsigned short* asrc = Ab + arow * (long)lda + ahf;
    const float* Bb = B + (EXPERT ? (long)e * sBe : 0L);

    for (int k0 = 0; k0 < Ktot; k0 += 32) {
        // ---- stage A tile (bf16 direct copy) ----
        uint4 av0 = {0, 0, 0, 0}, av1 = {0, 0, 0, 0};
        if (arow >= 0) {
            const uint4* p = (const uint4*)(asrc + k0);
            av0 = p[0]; av1 = p[1];
        }
        uint4* ad = (uint4*)(&As[ar * 40 + ahf]);
        ad[0] = av0; ad[1] = av1;
        // ---- stage B tile (fp32 -> bf16, transposed to [n][k]) ----
#pragma unroll
        for (int j = 0; j < 16; j++) {
            int idx = (j << 8) + tid;
            int kk = idx >> 7;
            int nn = idx & 127;
            float bv = Bb[(long)(k0 + kk) * ldb + (nbase + nn)];
            Bs[nn * 40 + kk] = f2bf(bv);
        }
        __syncthreads();
        short8 afr[4], bfr[4];
#pragma unroll
        for (int mi = 0; mi < 4; mi++)
            afr[mi] = *(const short8*)(&As[(wm * 64 + mi * 16 + lr) * 40 + lk * 8]);
#pragma unroll
        for (int ni = 0; ni < 4; ni++)
            bfr[ni] = *(const short8*)(&Bs[(wn * 64 + ni * 16 + lr) * 40 + lk * 8]);
#pragma unroll
        for (int mi = 0; mi < 4; mi++)
#pragma unroll
            for (int ni = 0; ni < 4; ni++)
                acc[mi][ni] = __builtin_amdgcn_mfma_f32_16x16x32_bf16(afr[mi], bfr[ni], acc[mi][ni], 0, 0, 0);
        __syncthreads();
    }

    // ---- epilogue: C/D layout col=lane&15, row=(lane>>4)*4+reg ----
    unsigned short* Cb = (unsigned short*)C;
    float* Cf = (float*)C;
    long cbase = (EXPERT && !SCATTER_C) ? (long)e * sCe : 0L;
#pragma unroll
    for (int mi = 0; mi < 4; mi++) {
#pragma unroll
        for (int j = 0; j < 4; j++) {
            int rowt = wm * 64 + mi * 16 + lk * 4 + j;
            int gr = mbase + rowt;
            if (gr >= Mlim) continue;
            long crow = SCATTER_C ? (long)scatter[(long)e * T_ + gr] : (long)gr;
            long rb = cbase + crow * (long)ldc;
#pragma unroll
            for (int ni = 0; ni < 4; ni++) {
                int col = nbase + wn * 64 + ni * 16 + lr;
                float v = acc[mi][ni][j];
                if (C_F32) Cf[rb + col] = v;
                else       Cb[rb + col] = f2bf(v);
            }
        }
    }
}

// ---------------- shared expert activation: c1 = silu(g) * u ----------------
__global__ void act_shared_kernel(const unsigned short* __restrict__ g,
                                  const unsigned short* __restrict__ u,
                                  unsigned short* __restrict__ c1, int n) {
    int i = blockIdx.x * blockDim.x + threadIdx.x;
    if (i >= n) return;
    float gv = bf2f(g[i]);
    float uv = bf2f(u[i]);
    float s = gv / (1.f + expf(-gv));
    c1[i] = f2bf(s * uv);
}

// ---------------- routed expert activation: clamped swiglu * weight ----------------
__global__ void act_expert_kernel(const unsigned short* __restrict__ g_e,
                                  const unsigned short* __restrict__ u_e,
                                  const float* __restrict__ wt_list,
                                  const int* __restrict__ counts, int cap,
                                  unsigned short* __restrict__ act) {
    int e = blockIdx.x, pos = blockIdx.y;
    int c = counts[e]; if (c > cap) c = cap;
    if (pos >= c) return;
    float w = wt_list[e * T_ + pos];
    long base = ((long)e * cap + pos) * I_;
    for (int i = threadIdx.x; i < I_; i += blockDim.x) {
        float gv = bf2f(g_e[base + i]);
        gv = fminf(gv, 7.f);
        float uv = bf2f(u_e[base + i]);
        uv = fminf(fmaxf(uv, -7.f), 7.f);
        float a = gv / (1.f + expf(-1.702f * gv)) * (uv + 1.f) * w;
        act[base + i] = f2bf(a);
    }
}

// ---------------- final: out += sum_k routed(t,k) ----------------
__global__ void final_add_kernel(float* __restrict__ out, const unsigned short* __restrict__ down) {
    int i = blockIdx.x * blockDim.x + threadIdx.x;  // one float4 of out
    int o = i * 4;
    int t = o >> 10;      // / H_
    int h = o & (H_ - 1);
    float4 v = ((float4*)out)[i];
#pragma unroll
    for (int k = 0; k < KSEL; k++) {
        const unsigned short* dr = down + ((long)(t * KSEL + k) << 10) + h;
        ushort4 d4 = *(const ushort4*)dr;
        v.x += bf2f(d4.x); v.y += bf2f(d4.y); v.z += bf2f(d4.z); v.w += bf2f(d4.w);
    }
    ((float4*)out)[i] = v;
}

extern "C" void kernel_launch(void* const* d_in, const int* in_sizes, int n_in,
                              void* d_out, int out_size, void* d_ws, size_t ws_size,
                              hipStream_t stream) {
    const float* x    = (const float*)d_in[0];
    // d_in[1] = input_ids (unused by reference math)
    const float* Wg   = (const float*)d_in[2];
    const float* bias = (const float*)d_in[3];
    const float* W1   = (const float*)d_in[4];
    const float* W3   = (const float*)d_in[5];
    const float* W2   = (const float*)d_in[6];
    const float* Wsg  = (const float*)d_in[7];
    const float* Wsu  = (const float*)d_in[8];
    const float* Wsd  = (const float*)d_in[9];
    float* out = (float*)d_out;
    char* ws = (char*)d_ws;

    size_t off = 0;
    auto carve = [&](size_t bytes) -> char* {
        char* p = ws + off;
        off = (off + bytes + 255) & ~(size_t)255;
        return p;
    };
    unsigned short* x_bf = (unsigned short*)carve((size_t)T_ * H_ * 2);
    unsigned short* g_sh = (unsigned short*)carve((size_t)T_ * IS_ * 2);
    unsigned short* u_sh = (unsigned short*)carve((size_t)T_ * IS_ * 2);
    unsigned short* c1   = (unsigned short*)carve((size_t)T_ * IS_ * 2);
    unsigned short* dwn  = (unsigned short*)carve((size_t)T_ * KSEL * H_ * 2);
    int* counts    = (int*)carve(E_ * sizeof(int));
    int* tok_list  = (int*)carve((size_t)E_ * T_ * 4);
    int* slot_list = (int*)carve((size_t)E_ * T_ * 4);
    float* wt_list = (float*)carve((size_t)E_ * T_ * 4);

    size_t remain = (ws_size > off) ? (ws_size - off) : 0;
    long cap = (long)(remain / ((size_t)3 * E_ * I_ * 2));
    if (cap > T_) cap = T_;
    cap = (cap / 128) * 128;
    if (cap < 128) cap = 128;
    unsigned short* g_e = (unsigned short*)carve((size_t)E_ * cap * I_ * 2);
    unsigned short* u_e = (unsigned short*)carve((size_t)E_ * cap * I_ * 2);
    unsigned short* act = (unsigned short*)carve((size_t)E_ * cap * I_ * 2);

    hipMemsetAsync(counts, 0, E_ * sizeof(int), stream);
    convert_kernel<<<(T_ * H_ / 4 + 255) / 256, 256, 0, stream>>>(x, x_bf, T_ * H_ / 4);
    router_kernel<<<T_, 64, 0, stream>>>(x, Wg, bias, counts, tok_list, slot_list, wt_list, (int)cap);

    dim3 blk(256);
    // shared experts: gate & up
    gemm_kernel<false, false, false, false><<<dim3(IS_ / 128, T_ / 128, 1), blk, 0, stream>>>(
        x_bf, H_, 0, Wsg, IS_, 0, (void*)g_sh, IS_, 0, T_, H_, nullptr, 0, nullptr, nullptr);
    gemm_kernel<false, false, false, false><<<dim3(IS_ / 128, T_ / 128, 1), blk, 0, stream>>>(
        x_bf, H_, 0, Wsu, IS_, 0, (void*)u_sh, IS_, 0, T_, H_, nullptr, 0, nullptr, nullptr);
    act_shared_kernel<<<(T_ * IS_ + 255) / 256, 256, 0, stream>>>(g_sh, u_sh, c1, T_ * IS_);
    // shared down -> d_out (fp32, full overwrite)
    gemm_kernel<false, false, false, true><<<dim3(H_ / 128, T_ / 128, 1), blk, 0, stream>>>(
        c1, IS_, 0, Wsd, H_, 0, (void*)out, H_, 0, T_, IS_, nullptr, 0, nullptr, nullptr);
    // routed experts: up (gathered rows)
    gemm_kernel<true, true, false, false><<<dim3(I_ / 128, cap / 128, E_), blk, 0, stream>>>(
        x_bf, H_, 0, W1, I_, (long)H_ * I_, (void*)g_e, I_, (long)cap * I_, 0, H_,
        counts, (int)cap, tok_list, nullptr);
    gemm_kernel<true, true, false, false><<<dim3(I_ / 128, cap / 128, E_), blk, 0, stream>>>(
        x_bf, H_, 0, W3, I_, (long)H_ * I_, (void*)u_e, I_, (long)cap * I_, 0, H_,
        counts, (int)cap, tok_list, nullptr);
    act_expert_kernel<<<dim3(E_, (unsigned)cap), 128, 0, stream>>>(g_e, u_e, wt_list, counts, (int)cap, act);
    // routed experts: down (scatter to per-(t,k) slots)
    gemm_kernel<true, false, true, false><<<dim3(H_ / 128, cap / 128, E_), blk, 0, stream>>>(
        act, I_, (long)cap * I_, W2, H_, (long)I_ * H_, (void*)dwn, H_, 0, 0, I_,
        counts, (int)cap, nullptr, slot_list);
    final_add_kernel<<<T_ * H_ / 4 / 256, 256, 0, stream>>>(out, dwn);
}

// Round 2
// 255.213 us; speedup vs baseline: 1.2636x; 1.2636x over previous
//
#include <hip/hip_runtime.h>
#include <hip/hip_bf16.h>
#include <math.h>

#define T_ 1024
#define H_ 1024
#define E_ 16
#define I_ 512
#define KSEL 4
#define IS_ 1024

typedef unsigned short u16;
typedef __attribute__((ext_vector_type(8))) short short8;
typedef __attribute__((ext_vector_type(4))) float f32x4;

__device__ __forceinline__ u16 f2bf(float f) {
    union { float f; unsigned int u; } v; v.f = f;
    unsigned int u = v.u;
    return (u16)((u + 0x7fffu + ((u >> 16) & 1u)) >> 16);
}
__device__ __forceinline__ float bf2f(u16 b) {
    union { unsigned int u; float f; } v; v.u = ((unsigned int)b) << 16;
    return v.f;
}

__device__ __forceinline__ void gload16(const u16* g, u16* l) {
    __builtin_amdgcn_global_load_lds(
        (const __attribute__((address_space(1))) void*)g,
        (__attribute__((address_space(3))) void*)l, 16, 0, 0);
}

// ---------------- x -> bf16 ----------------
__global__ void convert_kernel(const float* __restrict__ in, u16* __restrict__ out, int n4) {
    int i = blockIdx.x * blockDim.x + threadIdx.x;
    if (i >= n4) return;
    float4 v = ((const float4*)in)[i];
    ushort4 o;
    o.x = f2bf(v.x); o.y = f2bf(v.y); o.z = f2bf(v.z); o.w = f2bf(v.w);
    ((ushort4*)out)[i] = o;
}

// ---------------- fp32 [R][C] -> bf16 [C][R] tiled transpose ----------------
__global__ __launch_bounds__(256)
void transpose_bf16_kernel(const float* __restrict__ in, u16* __restrict__ out,
                           int ldin, int ldout, long sIn, long sOut) {
    __shared__ u16 tile[64 * 72];
    const float* ip = in + (long)blockIdx.z * sIn;
    u16* op = out + (long)blockIdx.z * sOut;
    int rb = blockIdx.y * 64, cb = blockIdx.x * 64;
    int tid = threadIdx.x;
    int r0 = (tid >> 4) * 4;
    int c4 = (tid & 15) * 4;
#pragma unroll
    for (int i = 0; i < 4; i++) {
        float4 v = *(const float4*)(ip + (long)(rb + r0 + i) * ldin + cb + c4);
        ushort4 o;
        o.x = f2bf(v.x); o.y = f2bf(v.y); o.z = f2bf(v.z); o.w = f2bf(v.w);
        *(ushort4*)&tile[(r0 + i) * 72 + c4] = o;
    }
    __syncthreads();
    int c = tid >> 2;
    int r16 = (tid & 3) * 16;
    short8 a, b;
#pragma unroll
    for (int j = 0; j < 8; j++) {
        a[j] = (short)tile[(r16 + j) * 72 + c];
        b[j] = (short)tile[(r16 + 8 + j) * 72 + c];
    }
    u16* orow = op + (long)(cb + c) * ldout + rb + r16;
    *(short8*)(orow) = a;
    *(short8*)(orow + 8) = b;
}

// ---------------- router: 1 wave per token ----------------
__global__ __launch_bounds__(256)
void router_kernel(const float* __restrict__ x, const float* __restrict__ Wg,
                   const float* __restrict__ bias, int* __restrict__ counts,
                   int* __restrict__ tok_list, int* __restrict__ slot_list,
                   float* __restrict__ wt_list, int cap) {
    int t = blockIdx.x * 4 + (threadIdx.x >> 6);
    int lane = threadIdx.x & 63;
    int e = lane & 15;        // expert
    int q = lane >> 4;        // H-quarter
    const float4* xv = (const float4*)(x + (long)t * H_ + q * 256);
    const float4* wv = (const float4*)(Wg + (long)e * H_ + q * 256);
    float d0 = 0.f, d1 = 0.f, d2 = 0.f, d3 = 0.f;
#pragma unroll
    for (int i = 0; i < 64; i += 4) {
        float4 a0 = xv[i],     b0 = wv[i];
        float4 a1 = xv[i + 1], b1 = wv[i + 1];
        float4 a2 = xv[i + 2], b2 = wv[i + 2];
        float4 a3 = xv[i + 3], b3 = wv[i + 3];
        d0 += a0.x * b0.x + a0.y * b0.y + a0.z * b0.z + a0.w * b0.w;
        d1 += a1.x * b1.x + a1.y * b1.y + a1.z * b1.z + a1.w * b1.w;
        d2 += a2.x * b2.x + a2.y * b2.y + a2.z * b2.z + a2.w * b2.w;
        d3 += a3.x * b3.x + a3.y * b3.y + a3.z * b3.z + a3.w * b3.w;
    }
    float d = (d0 + d1) + (d2 + d3);
    d += __shfl_xor(d, 16);
    d += __shfl_xor(d, 32);
    // every lane now holds the full logit for expert e
    float sp = fmaxf(d, 0.f) + log1pf(expf(-fabsf(d)));  // stable softplus
    float s = sqrtf(sp);
    float bs = s + bias[e];
    int sel[KSEL];
    float wv_sel[KSEL];
    float wsum = 0.f;
#pragma unroll
    for (int k = 0; k < KSEL; k++) {
        float mv = bs; int me = e;
#pragma unroll
        for (int off = 1; off < 16; off <<= 1) {
            float ov = __shfl_xor(mv, off);
            int oe = __shfl_xor(me, off);
            if (ov > mv || (ov == mv && oe < me)) { mv = ov; me = oe; }
        }
        sel[k] = me;
        float sk = __shfl(s, me);   // raw score of selected expert
        wv_sel[k] = sk;
        wsum += sk;
        if (e == me) bs = -1e30f;   // remove from candidates
    }
    float inv = 2.5f / wsum;
#pragma unroll
    for (int k = 0; k < KSEL; k++) {
        if (lane == k) {
            int se = sel[k];
            int pos = atomicAdd(&counts[se], 1);
            if (pos < cap) {
                tok_list[se * T_ + pos] = t;
                slot_list[se * T_ + pos] = t * KSEL + k;
                wt_list[se * T_ + pos] = wv_sel[k] * inv;
            }
        }
    }
}

// ---------------- m97-style bf16 GEMM: C[M,N] = A[M,K] * Bt[N,K]^T ----------------
template<bool EXPERT, bool GATHER_A, bool SCATTER_C, bool C_F32>
__global__ __launch_bounds__(256)
void gemm_bt_kernel(const u16* __restrict__ A, int lda, long sAe,
                    const u16* __restrict__ Bt, int ldb, long sBe,
                    void* __restrict__ C, int ldc, long sCe,
                    int Mfull, int Ktot,
                    const int* __restrict__ counts, int cap,
                    const int* __restrict__ gather, const int* __restrict__ scatter) {
    int e = 0, Mlim = Mfull;
    if (EXPERT) { e = blockIdx.z; int c = counts[e]; Mlim = c < cap ? c : cap; }
    int mbase = blockIdx.y * 128;
    if (mbase >= Mlim) return;
    int nbase = blockIdx.x * 128;

    __shared__ __align__(16) u16 As[128 * 32];
    __shared__ __align__(16) u16 Bs[128 * 32];

    int tid = threadIdx.x, lane = tid & 63, wid = tid >> 6;
    int sr = wid * 16 + (lane >> 2);   // staging row within 64-row half
    int sk = (lane & 3) * 8;           // staging k element offset

    const u16* Ab = A + ((EXPERT && !GATHER_A) ? (long)e * sAe : 0L);
    long ar0, ar1;
    {
        int gr = mbase + sr;
        int grc = gr < Mlim ? gr : (Mlim - 1);
        ar0 = GATHER_A ? (long)gather[e * T_ + grc] : (long)grc;
        gr = mbase + 64 + sr;
        grc = gr < Mlim ? gr : (Mlim - 1);
        ar1 = GATHER_A ? (long)gather[e * T_ + grc] : (long)grc;
    }
    const u16* aptr0 = Ab + ar0 * (long)lda + sk;
    const u16* aptr1 = Ab + ar1 * (long)lda + sk;
    const u16* Bb = Bt + (EXPERT ? (long)e * sBe : 0L);
    const u16* bptr0 = Bb + (long)(nbase + sr) * ldb + sk;
    const u16* bptr1 = Bb + (long)(nbase + 64 + sr) * ldb + sk;

    u16* asd = &As[wid * 512 + lane * 8];  // lane 0 == wave-uniform base
    u16* bsd = &Bs[wid * 512 + lane * 8];

    int wm = wid >> 1, wn = wid & 1;
    int lr = lane & 15, lk = lane >> 4;
    f32x4 acc[4][4] = {};

    for (int k0 = 0; k0 < Ktot; k0 += 32) {
        gload16(aptr0 + k0, asd);
        gload16(aptr1 + k0, asd + 2048);
        gload16(bptr0 + k0, bsd);
        gload16(bptr1 + k0, bsd + 2048);
        __syncthreads();   // drains vmcnt -> staged data visible
        short8 afr[4], bfr[4];
#pragma unroll
        for (int mi = 0; mi < 4; mi++)
            afr[mi] = *(const short8*)&As[(wm * 64 + mi * 16 + lr) * 32 + lk * 8];
#pragma unroll
        for (int ni = 0; ni < 4; ni++)
            bfr[ni] = *(const short8*)&Bs[(wn * 64 + ni * 16 + lr) * 32 + lk * 8];
#pragma unroll
        for (int mi = 0; mi < 4; mi++)
#pragma unroll
            for (int ni = 0; ni < 4; ni++)
                acc[mi][ni] = __builtin_amdgcn_mfma_f32_16x16x32_bf16(afr[mi], bfr[ni], acc[mi][ni], 0, 0, 0);
        __syncthreads();   // protect LDS before next overwrite
    }

    // epilogue: C/D layout col = lane&15, row = (lane>>4)*4 + reg
    u16* Cb = (u16*)C;
    float* Cf = (float*)C;
    long cbase = (EXPERT && !SCATTER_C) ? (long)e * sCe : 0L;
#pragma unroll
    for (int mi = 0; mi < 4; mi++) {
#pragma unroll
        for (int j = 0; j < 4; j++) {
            int rowt = wm * 64 + mi * 16 + lk * 4 + j;
            int gr = mbase + rowt;
            if (gr >= Mlim) continue;
            long crow = SCATTER_C ? (long)scatter[e * T_ + gr] : (long)gr;
            long rb = cbase + crow * (long)ldc;
#pragma unroll
            for (int ni = 0; ni < 4; ni++) {
                int col = nbase + wn * 64 + ni * 16 + lr;
                float v = acc[mi][ni][j];
                if (C_F32) Cf[rb + col] = v;
                else       Cb[rb + col] = f2bf(v);
            }
        }
    }
}

// ---------------- shared act: c1 = silu(g) * u, g/u interleaved [t][0..1023 | 1024..2047] ----
__global__ void act_shared_kernel(const u16* __restrict__ gu, u16* __restrict__ c1, int n4) {
    int i = blockIdx.x * blockDim.x + threadIdx.x;
    if (i >= n4) return;
    int t = (i << 2) >> 10;
    int o = (i << 2) & 1023;
    ushort4 g4 = *(const ushort4*)&gu[(long)t * 2048 + o];
    ushort4 u4 = *(const ushort4*)&gu[(long)t * 2048 + 1024 + o];
    ushort4 r;
    float g, u;
    g = bf2f(g4.x); u = bf2f(u4.x); r.x = f2bf(g / (1.f + expf(-g)) * u);
    g = bf2f(g4.y); u = bf2f(u4.y); r.y = f2bf(g / (1.f + expf(-g)) * u);
    g = bf2f(g4.z); u = bf2f(u4.z); r.z = f2bf(g / (1.f + expf(-g)) * u);
    g = bf2f(g4.w); u = bf2f(u4.w); r.w = f2bf(g / (1.f + expf(-g)) * u);
    *(ushort4*)&c1[(long)(i << 2)] = r;
}

// ---------------- routed act: clamped swiglu * weight, in-place over g half ----------------
__global__ void act_expert_kernel(u16* __restrict__ gu, const float* __restrict__ wt_list,
                                  const int* __restrict__ counts, int cap) {
    int e = blockIdx.x, pos = blockIdx.y;
    int c = counts[e]; if (c > cap) c = cap;
    if (pos >= c) return;
    float w = wt_list[e * T_ + pos];
    long base = ((long)e * cap + pos) * 1024;
    int o = threadIdx.x * 4;
    ushort4 g4 = *(const ushort4*)&gu[base + o];
    ushort4 u4 = *(const ushort4*)&gu[base + 512 + o];
    ushort4 r;
    float g, u;
    g = fminf(bf2f(g4.x), 7.f); u = fminf(fmaxf(bf2f(u4.x), -7.f), 7.f);
    r.x = f2bf(g / (1.f + expf(-1.702f * g)) * (u + 1.f) * w);
    g = fminf(bf2f(g4.y), 7.f); u = fminf(fmaxf(bf2f(u4.y), -7.f), 7.f);
    r.y = f2bf(g / (1.f + expf(-1.702f * g)) * (u + 1.f) * w);
    g = fminf(bf2f(g4.z), 7.f); u = fminf(fmaxf(bf2f(u4.z), -7.f), 7.f);
    r.z = f2bf(g / (1.f + expf(-1.702f * g)) * (u + 1.f) * w);
    g = fminf(bf2f(g4.w), 7.f); u = fminf(fmaxf(bf2f(u4.w), -7.f), 7.f);
    r.w = f2bf(g / (1.f + expf(-1.702f * g)) * (u + 1.f) * w);
    *(ushort4*)&gu[base + o] = r;
}

// ---------------- final: out += sum_k routed(t,k) ----------------
__global__ void final_add_kernel(float* __restrict__ out, const u16* __restrict__ down) {
    int i = blockIdx.x * blockDim.x + threadIdx.x;
    int o = i * 4;
    int t = o >> 10;
    int h = o & (H_ - 1);
    float4 v = ((float4*)out)[i];
#pragma unroll
    for (int k = 0; k < KSEL; k++) {
        const u16* dr = down + ((long)(t * KSEL + k) << 10) + h;
        ushort4 d4 = *(const ushort4*)dr;
        v.x += bf2f(d4.x); v.y += bf2f(d4.y); v.z += bf2f(d4.z); v.w += bf2f(d4.w);
    }
    ((float4*)out)[i] = v;
}

extern "C" void kernel_launch(void* const* d_in, const int* in_sizes, int n_in,
                              void* d_out, int out_size, void* d_ws, size_t ws_size,
                              hipStream_t stream) {
    const float* x    = (const float*)d_in[0];
    const float* Wg   = (const float*)d_in[2];
    const float* bias = (const float*)d_in[3];
    const float* W1   = (const float*)d_in[4];
    const float* W3   = (const float*)d_in[5];
    const float* W2   = (const float*)d_in[6];
    const float* Wsg  = (const float*)d_in[7];
    const float* Wsu  = (const float*)d_in[8];
    const float* Wsd  = (const float*)d_in[9];
    float* out = (float*)d_out;
    char* ws = (char*)d_ws;

    size_t off = 0;
    auto carve = [&](size_t bytes) -> char* {
        char* p = ws + off;
        off = (off + bytes + 255) & ~(size_t)255;
        return p;
    };
    u16* x_bf   = (u16*)carve((size_t)T_ * H_ * 2);            // 2 MB
    u16* gu_sh  = (u16*)carve((size_t)T_ * 2 * IS_ * 2);       // 4 MB
    u16* c1     = (u16*)carve((size_t)T_ * IS_ * 2);           // 2 MB
    u16* dwn    = (u16*)carve((size_t)T_ * KSEL * H_ * 2);     // 8 MB
    int* counts    = (int*)carve(E_ * sizeof(int));
    int* tok_list  = (int*)carve((size_t)E_ * T_ * 4);
    int* slot_list = (int*)carve((size_t)E_ * T_ * 4);
    float* wt_list = (float*)carve((size_t)E_ * T_ * 4);
    u16* Wsht   = (u16*)carve((size_t)2 * IS_ * H_ * 2);       // 4 MB (gate+up concat / Wsd^T reuse)
    u16* Wexp   = (u16*)carve((size_t)E_ * I_ * H_ * 2);       // 16 MB (W1^T / W3^T / W2^T reuse)

    size_t remain = (ws_size > off) ? (ws_size - off) : 0;
    long cap = (long)(remain / ((size_t)E_ * 1024 * 2));
    if (cap > T_) cap = T_;
    cap = (cap / 128) * 128;
    if (cap < 128) cap = 128;
    u16* gu_e = (u16*)carve((size_t)E_ * cap * 1024 * 2);
    int capB = (int)(cap / 128);

    hipMemsetAsync(counts, 0, E_ * sizeof(int), stream);
    convert_kernel<<<T_ * H_ / 4 / 256, 256, 0, stream>>>(x, x_bf, T_ * H_ / 4);
    router_kernel<<<T_ / 4, 256, 0, stream>>>(x, Wg, bias, counts, tok_list, slot_list, wt_list, (int)cap);

    dim3 blk(256);
    // ---- shared experts ----
    transpose_bf16_kernel<<<dim3(IS_ / 64, H_ / 64, 1), blk, 0, stream>>>(Wsg, Wsht, IS_, H_, 0, 0);
    transpose_bf16_kernel<<<dim3(IS_ / 64, H_ / 64, 1), blk, 0, stream>>>(Wsu, Wsht + (size_t)IS_ * H_, IS_, H_, 0, 0);
    gemm_bt_kernel<false, false, false, false><<<dim3(2 * IS_ / 128, T_ / 128, 1), blk, 0, stream>>>(
        x_bf, H_, 0, Wsht, H_, 0, (void*)gu_sh, 2 * IS_, 0, T_, H_, nullptr, 0, nullptr, nullptr);
    act_shared_kernel<<<T_ * IS_ / 4 / 256, 256, 0, stream>>>(gu_sh, c1, T_ * IS_ / 4);
    transpose_bf16_kernel<<<dim3(H_ / 64, IS_ / 64, 1), blk, 0, stream>>>(Wsd, Wsht, H_, IS_, 0, 0);
    gemm_bt_kernel<false, false, false, true><<<dim3(H_ / 128, T_ / 128, 1), blk, 0, stream>>>(
        c1, IS_, 0, Wsht, IS_, 0, (void*)out, H_, 0, T_, IS_, nullptr, 0, nullptr, nullptr);
    // ---- routed experts ----
    transpose_bf16_kernel<<<dim3(I_ / 64, H_ / 64, E_), blk, 0, stream>>>(W1, Wexp, I_, H_, (long)H_ * I_, (long)I_ * H_);
    gemm_bt_kernel<true, true, false, false><<<dim3(I_ / 128, capB, E_), blk, 0, stream>>>(
        x_bf, H_, 0, Wexp, H_, (long)I_ * H_, (void*)gu_e, 1024, (long)cap * 1024, 0, H_,
        counts, (int)cap, tok_list, nullptr);
    transpose_bf16_kernel<<<dim3(I_ / 64, H_ / 64, E_), blk, 0, stream>>>(W3, Wexp, I_, H_, (long)H_ * I_, (long)I_ * H_);
    gemm_bt_kernel<true, true, false, false><<<dim3(I_ / 128, capB, E_), blk, 0, stream>>>(
        x_bf, H_, 0, Wexp, H_, (long)I_ * H_, (void*)(gu_e + 512), 1024, (long)cap * 1024, 0, H_,
        counts, (int)cap, tok_list, nullptr);
    act_expert_kernel<<<dim3(E_, (unsigned)cap), 128, 0, stream>>>(gu_e, wt_list, counts, (int)cap);
    transpose_bf16_kernel<<<dim3(H_ / 64, I_ / 64, E_), blk, 0, stream>>>(W2, Wexp, H_, I_, (long)I_ * H_, (long)H_ * I_);
    gemm_bt_kernel<true, false, true, false><<<dim3(H_ / 128, capB, E_), blk, 0, stream>>>(
        gu_e, 1024, (long)cap * 1024, Wexp, I_, (long)H_ * I_, (void*)dwn, H_, 0, 0, I_,
        counts, (int)cap, nullptr, slot_list);
    final_add_kernel<<<T_ * H_ / 4 / 256, 256, 0, stream>>>(out, dwn);
}

// Round 3
// 180.186 us; speedup vs baseline: 1.7897x; 1.4164x over previous
//
#include <hip/hip_runtime.h>
#include <hip/hip_bf16.h>
#include <math.h>

#define T_ 1024
#define H_ 1024
#define E_ 16
#define I_ 512
#define KSEL 4
#define IS_ 1024

typedef unsigned short u16;
typedef __attribute__((ext_vector_type(8))) short short8;
typedef __attribute__((ext_vector_type(4))) float f32x4;

__device__ __forceinline__ u16 f2bf(float f) {
    union { float f; unsigned int u; } v; v.f = f;
    unsigned int u = v.u;
    return (u16)((u + 0x7fffu + ((u >> 16) & 1u)) >> 16);
}
__device__ __forceinline__ float bf2f(u16 b) {
    union { unsigned int u; float f; } v; v.u = ((unsigned int)b) << 16;
    return v.f;
}

__device__ __forceinline__ void gload16(const u16* g, u16* l) {
    __builtin_amdgcn_global_load_lds(
        (const __attribute__((address_space(1))) void*)g,
        (__attribute__((address_space(3))) void*)l, 16, 0, 0);
}

// ---------------- x -> bf16 ----------------
__global__ void convert_kernel(const float* __restrict__ in, u16* __restrict__ out, int n4) {
    int i = blockIdx.x * blockDim.x + threadIdx.x;
    if (i >= n4) return;
    float4 v = ((const float4*)in)[i];
    ushort4 o;
    o.x = f2bf(v.x); o.y = f2bf(v.y); o.z = f2bf(v.z); o.w = f2bf(v.w);
    ((ushort4*)out)[i] = o;
}

// ---------------- fp32 [R][C] -> bf16 [C][R] tiled transpose ----------------
__global__ __launch_bounds__(256)
void transpose_bf16_kernel(const float* __restrict__ in, u16* __restrict__ out,
                           int ldin, int ldout, long sIn, long sOut) {
    __shared__ u16 tile[64 * 72];
    const float* ip = in + (long)blockIdx.z * sIn;
    u16* op = out + (long)blockIdx.z * sOut;
    int rb = blockIdx.y * 64, cb = blockIdx.x * 64;
    int tid = threadIdx.x;
    int r0 = (tid >> 4) * 4;
    int c4 = (tid & 15) * 4;
#pragma unroll
    for (int i = 0; i < 4; i++) {
        float4 v = *(const float4*)(ip + (long)(rb + r0 + i) * ldin + cb + c4);
        ushort4 o;
        o.x = f2bf(v.x); o.y = f2bf(v.y); o.z = f2bf(v.z); o.w = f2bf(v.w);
        *(ushort4*)&tile[(r0 + i) * 72 + c4] = o;
    }
    __syncthreads();
    int c = tid >> 2;
    int r16 = (tid & 3) * 16;
    short8 a, b;
#pragma unroll
    for (int j = 0; j < 8; j++) {
        a[j] = (short)tile[(r16 + j) * 72 + c];
        b[j] = (short)tile[(r16 + 8 + j) * 72 + c];
    }
    u16* orow = op + (long)(cb + c) * ldout + rb + r16;
    *(short8*)(orow) = a;
    *(short8*)(orow + 8) = b;
}

// ---------------- router: 16 tokens/block, thread=(token,expert), fp32 exact ------
__global__ __launch_bounds__(256)
void router_kernel(const float* __restrict__ x, const float* __restrict__ Wg,
                   const float* __restrict__ bias, int* __restrict__ counts,
                   int* __restrict__ tok_list, int* __restrict__ slot_list,
                   float* __restrict__ wt_list, int cap) {
    __shared__ float xs[16 * 1024];   // 64 KB
    int tid = threadIdx.x;
    int tb = blockIdx.x * 16;
    const float4* xg = (const float4*)(x + (long)tb * H_);
#pragma unroll
    for (int j = 0; j < 16; j++)
        ((float4*)xs)[j * 256 + tid] = xg[j * 256 + tid];
    __syncthreads();
    int t = tid >> 4;         // local token 0..15
    int e = tid & 15;         // expert
    int lane = tid & 63;
    const float4* wv = (const float4*)(Wg + e * H_);
    const float4* xv = (const float4*)(xs + t * 1024);
    float d = 0.f;
#pragma unroll 8
    for (int i = 0; i < 256; i++) {
        float4 a = xv[i], b = wv[i];
        d += a.x * b.x + a.y * b.y + a.z * b.z + a.w * b.w;
    }
    float sp = fmaxf(d, 0.f) + log1pf(expf(-fabsf(d)));  // stable softplus
    float s = sqrtf(sp);
    float bs = s + bias[e];
    int sel[KSEL]; float ssel[KSEL]; float wsum = 0.f;
#pragma unroll
    for (int k = 0; k < KSEL; k++) {
        float mv = bs; int me = e;
#pragma unroll
        for (int off = 1; off < 16; off <<= 1) {   // stays within 16-lane group
            float ov = __shfl_xor(mv, off);
            int oe = __shfl_xor(me, off);
            if (ov > mv || (ov == mv && oe < me)) { mv = ov; me = oe; }
        }
        sel[k] = me;
        float sk = __shfl(s, (lane & 48) | me);    // raw score of winner, same group
        ssel[k] = sk;
        wsum += sk;
        if (e == me) bs = -1e30f;
    }
    float inv = 2.5f / wsum;
    if (e < KSEL) {
        int k = e;
        int se = sel[k];
        int gt = tb + t;
        int pos = atomicAdd(&counts[se], 1);
        if (pos < cap) {
            tok_list[se * T_ + pos] = gt;
            slot_list[se * T_ + pos] = gt * KSEL + k;
            wt_list[se * T_ + pos] = ssel[k] * inv;
        }
    }
}

// ---------------- pipelined bf16 GEMM: C[M,N] = A[M,K] * Bt[N,K]^T ----------------
// BK=64, double-buffered LDS, T2 swizzle (pre-swizzled source, swizzled ds_read),
// 2-phase: stage(t+1) issued before compute(t), one __syncthreads per tile.
template<bool EXPERT, bool GATHER_A, bool SCATTER_C, bool C_F32>
__global__ __launch_bounds__(256)
void gemm_bt_kernel(const u16* __restrict__ A, int lda, long sAe,
                    const u16* __restrict__ Bt, int ldb, long sBe,
                    void* __restrict__ C, int ldc, long sCe,
                    int Mfull, int Ktot,
                    const int* __restrict__ counts, int cap,
                    const int* __restrict__ gather, const int* __restrict__ scatter) {
    int e = 0, Mlim = Mfull;
    if (EXPERT) { e = blockIdx.z; int c = counts[e]; Mlim = c < cap ? c : cap; }
    int mbase = blockIdx.y * 128;
    if (mbase >= Mlim) return;
    int nbase = blockIdx.x * 128;

    __shared__ __align__(16) u16 As[2][128 * 64];
    __shared__ __align__(16) u16 Bs[2][128 * 64];

    int tid = threadIdx.x;
    int lane = tid & 63, wid = tid >> 6;
    int srow = tid >> 3;              // staging row 0..31 (+ j*32)
    int sc = tid & 7;                 // 16B chunk in row
    int ssrc = ((sc ^ (srow & 7)) << 3);  // pre-swizzled source k-offset (u16)

    const u16* Ab = A + ((EXPERT && !GATHER_A) ? (long)e * sAe : 0L);
    const u16* Bb = Bt + (EXPERT ? (long)e * sBe : 0L);
    const u16* aptr[4];
    const u16* bptr[4];
#pragma unroll
    for (int j = 0; j < 4; j++) {
        int gr = mbase + j * 32 + srow;
        int grc = gr < Mlim ? gr : (Mlim - 1);
        long ar = GATHER_A ? (long)gather[e * T_ + grc] : (long)grc;
        aptr[j] = Ab + ar * (long)lda + ssrc;
        bptr[j] = Bb + (long)(nbase + j * 32 + srow) * ldb + ssrc;
    }
    u16* asb = &As[0][0];
    u16* bsb = &Bs[0][0];
    u16* adst = asb + tid * 8;   // linear dest: wave base + lane*16B
    u16* bdst = bsb + tid * 8;

    int wm = wid >> 1, wn = wid & 1;
    int lr = lane & 15, lk = lane >> 4;
    f32x4 acc[4][4] = {};

    int nt = Ktot >> 6;
    // prologue: stage tile 0
#pragma unroll
    for (int j = 0; j < 4; j++) {
        gload16(aptr[j], adst + j * 2048);
        gload16(bptr[j], bdst + j * 2048);
    }
    __syncthreads();

    for (int t = 0; t < nt; t++) {
        int cur = t & 1;
        if (t + 1 < nt) {
            int k0 = (t + 1) << 6;
            int bo = (cur ^ 1) * 8192;
#pragma unroll
            for (int j = 0; j < 4; j++) {
                gload16(aptr[j] + k0, adst + bo + j * 2048);
                gload16(bptr[j] + k0, bdst + bo + j * 2048);
            }
        }
        const u16* Asc = asb + cur * 8192;
        const u16* Bsc = bsb + cur * 8192;
#pragma unroll
        for (int kk = 0; kk < 2; kk++) {
            short8 afr[4], bfr[4];
#pragma unroll
            for (int mi = 0; mi < 4; mi++) {
                int R = wm * 64 + mi * 16 + lr;
                afr[mi] = *(const short8*)&Asc[R * 64 + ((((kk << 2) + lk) ^ (R & 7)) << 3)];
            }
#pragma unroll
            for (int ni = 0; ni < 4; ni++) {
                int R = wn * 64 + ni * 16 + lr;
                bfr[ni] = *(const short8*)&Bsc[R * 64 + ((((kk << 2) + lk) ^ (R & 7)) << 3)];
            }
#pragma unroll
            for (int mi = 0; mi < 4; mi++)
#pragma unroll
                for (int ni = 0; ni < 4; ni++)
                    acc[mi][ni] = __builtin_amdgcn_mfma_f32_16x16x32_bf16(afr[mi], bfr[ni], acc[mi][ni], 0, 0, 0);
        }
        __syncthreads();   // vmcnt(0)+lgkmcnt(0)+barrier: prefetch landed, reads done
    }

    // epilogue: C/D layout col = lane&15, row = (lane>>4)*4 + reg
    u16* Cb = (u16*)C;
    float* Cf = (float*)C;
    long cbase = (EXPERT && !SCATTER_C) ? (long)e * sCe : 0L;
#pragma unroll
    for (int mi = 0; mi < 4; mi++) {
#pragma unroll
        for (int j = 0; j < 4; j++) {
            int rowt = wm * 64 + mi * 16 + lk * 4 + j;
            int gr = mbase + rowt;
            if (gr >= Mlim) continue;
            long crow = SCATTER_C ? (long)scatter[e * T_ + gr] : (long)gr;
            long rb = cbase + crow * (long)ldc;
#pragma unroll
            for (int ni = 0; ni < 4; ni++) {
                int col = nbase + wn * 64 + ni * 16 + lr;
                float v = acc[mi][ni][j];
                if (C_F32) Cf[rb + col] = v;
                else       Cb[rb + col] = f2bf(v);
            }
        }
    }
}

// ---------------- shared act: c1 = silu(g) * u, gu layout [t][g(1024) | u(1024)] ----
__global__ void act_shared_kernel(const u16* __restrict__ gu, u16* __restrict__ c1, int n4) {
    int i = blockIdx.x * blockDim.x + threadIdx.x;
    if (i >= n4) return;
    int t = (i << 2) >> 10;
    int o = (i << 2) & 1023;
    ushort4 g4 = *(const ushort4*)&gu[(long)t * 2048 + o];
    ushort4 u4 = *(const ushort4*)&gu[(long)t * 2048 + 1024 + o];
    ushort4 r;
    float g, u;
    g = bf2f(g4.x); u = bf2f(u4.x); r.x = f2bf(g / (1.f + expf(-g)) * u);
    g = bf2f(g4.y); u = bf2f(u4.y); r.y = f2bf(g / (1.f + expf(-g)) * u);
    g = bf2f(g4.z); u = bf2f(u4.z); r.z = f2bf(g / (1.f + expf(-g)) * u);
    g = bf2f(g4.w); u = bf2f(u4.w); r.w = f2bf(g / (1.f + expf(-g)) * u);
    *(ushort4*)&c1[(long)(i << 2)] = r;
}

// ---------------- routed act: clamped swiglu * weight, in-place over g half --------
__global__ void act_expert_kernel(u16* __restrict__ gu, const float* __restrict__ wt_list,
                                  const int* __restrict__ counts, int cap) {
    int e = blockIdx.x, pos = blockIdx.y;
    int c = counts[e]; if (c > cap) c = cap;
    if (pos >= c) return;
    float w = wt_list[e * T_ + pos];
    long base = ((long)e * cap + pos) * 1024;
    int o = threadIdx.x * 4;
    ushort4 g4 = *(const ushort4*)&gu[base + o];
    ushort4 u4 = *(const ushort4*)&gu[base + 512 + o];
    ushort4 r;
    float g, u;
    g = fminf(bf2f(g4.x), 7.f); u = fminf(fmaxf(bf2f(u4.x), -7.f), 7.f);
    r.x = f2bf(g / (1.f + expf(-1.702f * g)) * (u + 1.f) * w);
    g = fminf(bf2f(g4.y), 7.f); u = fminf(fmaxf(bf2f(u4.y), -7.f), 7.f);
    r.y = f2bf(g / (1.f + expf(-1.702f * g)) * (u + 1.f) * w);
    g = fminf(bf2f(g4.z), 7.f); u = fminf(fmaxf(bf2f(u4.z), -7.f), 7.f);
    r.z = f2bf(g / (1.f + expf(-1.702f * g)) * (u + 1.f) * w);
    g = fminf(bf2f(g4.w), 7.f); u = fminf(fmaxf(bf2f(u4.w), -7.f), 7.f);
    r.w = f2bf(g / (1.f + expf(-1.702f * g)) * (u + 1.f) * w);
    *(ushort4*)&gu[base + o] = r;
}

// ---------------- final: out += sum_k routed(t,k) ----------------
__global__ void final_add_kernel(float* __restrict__ out, const u16* __restrict__ down) {
    int i = blockIdx.x * blockDim.x + threadIdx.x;
    int o = i * 4;
    int t = o >> 10;
    int h = o & (H_ - 1);
    float4 v = ((float4*)out)[i];
#pragma unroll
    for (int k = 0; k < KSEL; k++) {
        const u16* dr = down + ((long)(t * KSEL + k) << 10) + h;
        ushort4 d4 = *(const ushort4*)dr;
        v.x += bf2f(d4.x); v.y += bf2f(d4.y); v.z += bf2f(d4.z); v.w += bf2f(d4.w);
    }
    ((float4*)out)[i] = v;
}

extern "C" void kernel_launch(void* const* d_in, const int* in_sizes, int n_in,
                              void* d_out, int out_size, void* d_ws, size_t ws_size,
                              hipStream_t stream) {
    const float* x    = (const float*)d_in[0];
    const float* Wg   = (const float*)d_in[2];
    const float* bias = (const float*)d_in[3];
    const float* W1   = (const float*)d_in[4];
    const float* W3   = (const float*)d_in[5];
    const float* W2   = (const float*)d_in[6];
    const float* Wsg  = (const float*)d_in[7];
    const float* Wsu  = (const float*)d_in[8];
    const float* Wsd  = (const float*)d_in[9];
    float* out = (float*)d_out;
    char* ws = (char*)d_ws;

    size_t off = 0;
    auto carve = [&](size_t bytes) -> char* {
        char* p = ws + off;
        off = (off + bytes + 255) & ~(size_t)255;
        return p;
    };
    u16* x_bf   = (u16*)carve((size_t)T_ * H_ * 2);                 // 2 MB
    u16* gu_sh  = (u16*)carve((size_t)T_ * 2 * IS_ * 2);            // 4 MB
    u16* c1     = (u16*)carve((size_t)T_ * IS_ * 2);                // 2 MB
    u16* Wsht   = (u16*)carve((size_t)2 * IS_ * H_ * 2);            // 4 MB
    u16* dwn    = gu_sh;   // alias: 8 MB over gu_sh+c1+Wsht[0:2MB], all dead by then
    int* counts    = (int*)carve(E_ * sizeof(int));
    int* tok_list  = (int*)carve((size_t)E_ * T_ * 4);
    int* slot_list = (int*)carve((size_t)E_ * T_ * 4);
    float* wt_list = (float*)carve((size_t)E_ * T_ * 4);
    u16* W13t   = (u16*)carve((size_t)E_ * 2 * I_ * H_ * 2);        // 32 MB (W1^T;W3^T / W2^T reuse)

    size_t remain = (ws_size > off) ? (ws_size - off) : 0;
    long cap = (long)(remain / ((size_t)E_ * 1024 * 2));
    if (cap > 768) cap = 768;
    cap = (cap / 128) * 128;
    if (cap < 128) cap = 128;
    u16* gu_e = (u16*)carve((size_t)E_ * cap * 1024 * 2);
    int capB = (int)(cap / 128);

    hipMemsetAsync(counts, 0, E_ * sizeof(int), stream);
    convert_kernel<<<T_ * H_ / 4 / 256, 256, 0, stream>>>(x, x_bf, T_ * H_ / 4);
    router_kernel<<<T_ / 16, 256, 0, stream>>>(x, Wg, bias, counts, tok_list, slot_list, wt_list, (int)cap);

    dim3 blk(256);
    // ---- shared experts: [Wsg^T ; Wsu^T] one GEMM N=2048 ----
    transpose_bf16_kernel<<<dim3(IS_ / 64, H_ / 64, 1), blk, 0, stream>>>(Wsg, Wsht, IS_, H_, 0, 0);
    transpose_bf16_kernel<<<dim3(IS_ / 64, H_ / 64, 1), blk, 0, stream>>>(Wsu, Wsht + (size_t)IS_ * H_, IS_, H_, 0, 0);
    gemm_bt_kernel<false, false, false, false><<<dim3(2 * IS_ / 128, T_ / 128, 1), blk, 0, stream>>>(
        x_bf, H_, 0, Wsht, H_, 0, (void*)gu_sh, 2 * IS_, 0, T_, H_, nullptr, 0, nullptr, nullptr);
    act_shared_kernel<<<T_ * IS_ / 4 / 256, 256, 0, stream>>>(gu_sh, c1, T_ * IS_ / 4);
    transpose_bf16_kernel<<<dim3(H_ / 64, IS_ / 64, 1), blk, 0, stream>>>(Wsd, Wsht, H_, IS_, 0, 0);
    gemm_bt_kernel<false, false, false, true><<<dim3(H_ / 128, T_ / 128, 1), blk, 0, stream>>>(
        c1, IS_, 0, Wsht, IS_, 0, (void*)out, H_, 0, T_, IS_, nullptr, 0, nullptr, nullptr);
    // ---- routed experts: [W1^T ; W3^T] per expert, one up-GEMM N=1024 ----
    transpose_bf16_kernel<<<dim3(I_ / 64, H_ / 64, E_), blk, 0, stream>>>(
        W1, W13t, I_, H_, (long)H_ * I_, (long)2 * I_ * H_);
    transpose_bf16_kernel<<<dim3(I_ / 64, H_ / 64, E_), blk, 0, stream>>>(
        W3, W13t + (size_t)I_ * H_, I_, H_, (long)H_ * I_, (long)2 * I_ * H_);
    gemm_bt_kernel<true, true, false, false><<<dim3(1024 / 128, capB, E_), blk, 0, stream>>>(
        x_bf, H_, 0, W13t, H_, (long)2 * I_ * H_, (void*)gu_e, 1024, (long)cap * 1024, 0, H_,
        counts, (int)cap, tok_list, nullptr);
    act_expert_kernel<<<dim3(E_, (unsigned)cap), 128, 0, stream>>>(gu_e, wt_list, counts, (int)cap);
    transpose_bf16_kernel<<<dim3(H_ / 64, I_ / 64, E_), blk, 0, stream>>>(
        W2, W13t, H_, I_, (long)I_ * H_, (long)H_ * I_);
    gemm_bt_kernel<true, false, true, false><<<dim3(H_ / 128, capB, E_), blk, 0, stream>>>(
        gu_e, 1024, (long)cap * 1024, W13t, I_, (long)H_ * I_, (void*)dwn, H_, 0, 0, I_,
        counts, (int)cap, nullptr, slot_list);
    final_add_kernel<<<T_ * H_ / 4 / 256, 256, 0, stream>>>(out, dwn);
}

// Round 4
// 152.988 us; speedup vs baseline: 2.1079x; 1.1778x over previous
//
#include <hip/hip_runtime.h>
#include <hip/hip_bf16.h>
#include <math.h>

#define T_ 1024
#define H_ 1024
#define E_ 16
#define I_ 512
#define KSEL 4
#define IS_ 1024

typedef unsigned short u16;
typedef __attribute__((ext_vector_type(8))) short short8;
typedef __attribute__((ext_vector_type(4))) float f32x4;

__device__ __forceinline__ u16 f2bf(float f) {
    union { float f; unsigned int u; } v; v.f = f;
    unsigned int u = v.u;
    return (u16)((u + 0x7fffu + ((u >> 16) & 1u)) >> 16);
}
__device__ __forceinline__ float bf2f(u16 b) {
    union { unsigned int u; float f; } v; v.u = ((unsigned int)b) << 16;
    return v.f;
}

__device__ __forceinline__ void gload16(const u16* g, u16* l) {
    __builtin_amdgcn_global_load_lds(
        (const __attribute__((address_space(1))) void*)g,
        (__attribute__((address_space(3))) void*)l, 16, 0, 0);
}

// ---------------- x -> bf16 ----------------
__global__ void convert_kernel(const float* __restrict__ in, u16* __restrict__ out, int n4) {
    int i = blockIdx.x * blockDim.x + threadIdx.x;
    if (i >= n4) return;
    float4 v = ((const float4*)in)[i];
    ushort4 o;
    o.x = f2bf(v.x); o.y = f2bf(v.y); o.z = f2bf(v.z); o.w = f2bf(v.w);
    ((ushort4*)out)[i] = o;
}

// ------- dual-source fp32 [R][C] -> bf16 [C][R] tiled transpose (z-selected) -------
__global__ __launch_bounds__(256)
void transpose2_bf16_kernel(const float* __restrict__ s0, const float* __restrict__ s1,
                            u16* __restrict__ out, int ldin, int ldout,
                            long sIn, long sOut, int zsplit, long dOff1) {
    int z = blockIdx.z;
    const float* ip;
    u16* op;
    if (z < zsplit) { ip = s0 + (long)z * sIn; op = out + (long)z * sOut; }
    else { int z2 = z - zsplit; ip = s1 + (long)z2 * sIn; op = out + (long)z2 * sOut + dOff1; }
    __shared__ u16 tile[64 * 72];
    int rb = blockIdx.y * 64, cb = blockIdx.x * 64;
    int tid = threadIdx.x;
    int r0 = (tid >> 4) * 4;
    int c4 = (tid & 15) * 4;
#pragma unroll
    for (int i = 0; i < 4; i++) {
        float4 v = *(const float4*)(ip + (long)(rb + r0 + i) * ldin + cb + c4);
        ushort4 o;
        o.x = f2bf(v.x); o.y = f2bf(v.y); o.z = f2bf(v.z); o.w = f2bf(v.w);
        *(ushort4*)&tile[(r0 + i) * 72 + c4] = o;
    }
    __syncthreads();
    int c = tid >> 2;
    int r16 = (tid & 3) * 16;
    short8 a, b;
#pragma unroll
    for (int j = 0; j < 8; j++) {
        a[j] = (short)tile[(r16 + j) * 72 + c];
        b[j] = (short)tile[(r16 + 8 + j) * 72 + c];
    }
    u16* orow = op + (long)(cb + c) * ldout + rb + r16;
    *(short8*)(orow) = a;
    *(short8*)(orow + 8) = b;
}

// ---------------- router v3: 1 block/token, thread=(expert, H-chunk) ----------------
__global__ __launch_bounds__(256)
void router_kernel(const float* __restrict__ x, const float* __restrict__ Wg,
                   const float* __restrict__ bias, int* __restrict__ counts,
                   int* __restrict__ tok_list, int* __restrict__ slot_list,
                   float* __restrict__ wt_list, int cap) {
    __shared__ float part[4][16];
    int t = blockIdx.x;
    int tid = threadIdx.x;
    int e = tid & 15;
    int q = tid >> 4;   // 0..15, 64-element chunk
    const float4* xv = (const float4*)(x + (long)t * H_) + q * 16;
    const float4* wv = (const float4*)(Wg + (long)e * H_) + q * 16;
    float d = 0.f;
#pragma unroll
    for (int i = 0; i < 16; i++) {
        float4 a = xv[i], b = wv[i];
        d += a.x * b.x + a.y * b.y + a.z * b.z + a.w * b.w;
    }
    // sum the 4 q-chunks within this wave (lanes e, e+16, e+32, e+48)
    d += __shfl_down(d, 16);
    d += __shfl_down(d, 32);
    if ((tid & 63) < 16) part[tid >> 6][e] = d;
    __syncthreads();
    if (tid >= 64) return;
    int lane = tid;
    float lg = part[0][e] + part[1][e] + part[2][e] + part[3][e];
    float sp = fmaxf(lg, 0.f) + log1pf(expf(-fabsf(lg)));  // stable softplus
    float s = sqrtf(sp);
    float bs = s + bias[e];
    int sel[KSEL]; float ssel[KSEL]; float wsum = 0.f;
#pragma unroll
    for (int k = 0; k < KSEL; k++) {
        float mv = bs; int me = e;
#pragma unroll
        for (int off = 1; off < 16; off <<= 1) {   // butterfly within 16-lane group
            float ov = __shfl_xor(mv, off);
            int oe = __shfl_xor(me, off);
            if (ov > mv || (ov == mv && oe < me)) { mv = ov; me = oe; }
        }
        sel[k] = me;
        float sk = __shfl(s, (lane & 48) | me);   // winner's raw score, same group
        ssel[k] = sk; wsum += sk;
        if (e == me) bs = -1e30f;
    }
    float inv = 2.5f / wsum;
    if (lane < KSEL) {
        int k = lane;
        int se = sel[k];
        int pos = atomicAdd(&counts[se], 1);
        if (pos < cap) {
            tok_list[se * T_ + pos] = t;
            slot_list[se * T_ + pos] = t * KSEL + k;
            wt_list[se * T_ + pos] = ssel[k] * inv;
        }
    }
}

// ---------------- pipelined bf16 GEMM: C[M,N] = A[M,K] * Bt[N,K]^T ----------------
template<bool EXPERT, bool GATHER_A, bool SCATTER_C, bool C_F32>
__global__ __launch_bounds__(256)
void gemm_bt_kernel(const u16* __restrict__ A, int lda, long sAe,
                    const u16* __restrict__ Bt, int ldb, long sBe,
                    void* __restrict__ C, int ldc, long sCe,
                    int Mfull, int Ktot,
                    const int* __restrict__ counts, int cap,
                    const int* __restrict__ gather, const int* __restrict__ scatter) {
    int e = 0, Mlim = Mfull;
    if (EXPERT) { e = blockIdx.z; int c = counts[e]; Mlim = c < cap ? c : cap; }
    int mbase = blockIdx.y * 128;
    if (mbase >= Mlim) return;
    int nbase = blockIdx.x * 128;

    __shared__ __align__(16) u16 As[2][128 * 64];
    __shared__ __align__(16) u16 Bs[2][128 * 64];

    int tid = threadIdx.x;
    int lane = tid & 63, wid = tid >> 6;
    int srow = tid >> 3;
    int sc = tid & 7;
    int ssrc = ((sc ^ (srow & 7)) << 3);

    const u16* Ab = A + ((EXPERT && !GATHER_A) ? (long)e * sAe : 0L);
    const u16* Bb = Bt + (EXPERT ? (long)e * sBe : 0L);
    const u16* aptr[4];
    const u16* bptr[4];
#pragma unroll
    for (int j = 0; j < 4; j++) {
        int gr = mbase + j * 32 + srow;
        int grc = gr < Mlim ? gr : (Mlim - 1);
        long ar = GATHER_A ? (long)gather[e * T_ + grc] : (long)grc;
        aptr[j] = Ab + ar * (long)lda + ssrc;
        bptr[j] = Bb + (long)(nbase + j * 32 + srow) * ldb + ssrc;
    }
    u16* asb = &As[0][0];
    u16* bsb = &Bs[0][0];
    u16* adst = asb + tid * 8;
    u16* bdst = bsb + tid * 8;

    int wm = wid >> 1, wn = wid & 1;
    int lr = lane & 15, lk = lane >> 4;
    f32x4 acc[4][4] = {};

    int nt = Ktot >> 6;
#pragma unroll
    for (int j = 0; j < 4; j++) {
        gload16(aptr[j], adst + j * 2048);
        gload16(bptr[j], bdst + j * 2048);
    }
    __syncthreads();

    for (int t = 0; t < nt; t++) {
        int cur = t & 1;
        if (t + 1 < nt) {
            int k0 = (t + 1) << 6;
            int bo = (cur ^ 1) * 8192;
#pragma unroll
            for (int j = 0; j < 4; j++) {
                gload16(aptr[j] + k0, adst + bo + j * 2048);
                gload16(bptr[j] + k0, bdst + bo + j * 2048);
            }
        }
        const u16* Asc = asb + cur * 8192;
        const u16* Bsc = bsb + cur * 8192;
#pragma unroll
        for (int kk = 0; kk < 2; kk++) {
            short8 afr[4], bfr[4];
#pragma unroll
            for (int mi = 0; mi < 4; mi++) {
                int R = wm * 64 + mi * 16 + lr;
                afr[mi] = *(const short8*)&Asc[R * 64 + ((((kk << 2) + lk) ^ (R & 7)) << 3)];
            }
#pragma unroll
            for (int ni = 0; ni < 4; ni++) {
                int R = wn * 64 + ni * 16 + lr;
                bfr[ni] = *(const short8*)&Bsc[R * 64 + ((((kk << 2) + lk) ^ (R & 7)) << 3)];
            }
#pragma unroll
            for (int mi = 0; mi < 4; mi++)
#pragma unroll
                for (int ni = 0; ni < 4; ni++)
                    acc[mi][ni] = __builtin_amdgcn_mfma_f32_16x16x32_bf16(afr[mi], bfr[ni], acc[mi][ni], 0, 0, 0);
        }
        __syncthreads();
    }

    u16* Cb = (u16*)C;
    float* Cf = (float*)C;
    long cbase = (EXPERT && !SCATTER_C) ? (long)e * sCe : 0L;
#pragma unroll
    for (int mi = 0; mi < 4; mi++) {
#pragma unroll
        for (int j = 0; j < 4; j++) {
            int rowt = wm * 64 + mi * 16 + lk * 4 + j;
            int gr = mbase + rowt;
            if (gr >= Mlim) continue;
            long crow = SCATTER_C ? (long)scatter[e * T_ + gr] : (long)gr;
            long rb = cbase + crow * (long)ldc;
#pragma unroll
            for (int ni = 0; ni < 4; ni++) {
                int col = nbase + wn * 64 + ni * 16 + lr;
                float v = acc[mi][ni][j];
                if (C_F32) Cf[rb + col] = v;
                else       Cb[rb + col] = f2bf(v);
            }
        }
    }
}

// ---------------- shared act: c1 = silu(g) * u, gu layout [t][g(1024) | u(1024)] ----
__global__ void act_shared_kernel(const u16* __restrict__ gu, u16* __restrict__ c1, int n4) {
    int i = blockIdx.x * blockDim.x + threadIdx.x;
    if (i >= n4) return;
    int t = (i << 2) >> 10;
    int o = (i << 2) & 1023;
    ushort4 g4 = *(const ushort4*)&gu[(long)t * 2048 + o];
    ushort4 u4 = *(const ushort4*)&gu[(long)t * 2048 + 1024 + o];
    ushort4 r;
    float g, u;
    g = bf2f(g4.x); u = bf2f(u4.x); r.x = f2bf(g / (1.f + expf(-g)) * u);
    g = bf2f(g4.y); u = bf2f(u4.y); r.y = f2bf(g / (1.f + expf(-g)) * u);
    g = bf2f(g4.z); u = bf2f(u4.z); r.z = f2bf(g / (1.f + expf(-g)) * u);
    g = bf2f(g4.w); u = bf2f(u4.w); r.w = f2bf(g / (1.f + expf(-g)) * u);
    *(ushort4*)&c1[(long)(i << 2)] = r;
}

// ---------------- routed act: clamped swiglu * weight, in-place over g half --------
__global__ void act_expert_kernel(u16* __restrict__ gu, const float* __restrict__ wt_list,
                                  const int* __restrict__ counts, int cap) {
    int e = blockIdx.x, pos = blockIdx.y;
    int c = counts[e]; if (c > cap) c = cap;
    if (pos >= c) return;
    float w = wt_list[e * T_ + pos];
    long base = ((long)e * cap + pos) * 1024;
    int o = threadIdx.x * 4;
    ushort4 g4 = *(const ushort4*)&gu[base + o];
    ushort4 u4 = *(const ushort4*)&gu[base + 512 + o];
    ushort4 r;
    float g, u;
    g = fminf(bf2f(g4.x), 7.f); u = fminf(fmaxf(bf2f(u4.x), -7.f), 7.f);
    r.x = f2bf(g / (1.f + expf(-1.702f * g)) * (u + 1.f) * w);
    g = fminf(bf2f(g4.y), 7.f); u = fminf(fmaxf(bf2f(u4.y), -7.f), 7.f);
    r.y = f2bf(g / (1.f + expf(-1.702f * g)) * (u + 1.f) * w);
    g = fminf(bf2f(g4.z), 7.f); u = fminf(fmaxf(bf2f(u4.z), -7.f), 7.f);
    r.z = f2bf(g / (1.f + expf(-1.702f * g)) * (u + 1.f) * w);
    g = fminf(bf2f(g4.w), 7.f); u = fminf(fmaxf(bf2f(u4.w), -7.f), 7.f);
    r.w = f2bf(g / (1.f + expf(-1.702f * g)) * (u + 1.f) * w);
    *(ushort4*)&gu[base + o] = r;
}

// ---------------- final: out += sum_k routed(t,k) ----------------
__global__ void final_add_kernel(float* __restrict__ out, const u16* __restrict__ down) {
    int i = blockIdx.x * blockDim.x + threadIdx.x;
    int o = i * 4;
    int t = o >> 10;
    int h = o & (H_ - 1);
    float4 v = ((float4*)out)[i];
#pragma unroll
    for (int k = 0; k < KSEL; k++) {
        const u16* dr = down + ((long)(t * KSEL + k) << 10) + h;
        ushort4 d4 = *(const ushort4*)dr;
        v.x += bf2f(d4.x); v.y += bf2f(d4.y); v.z += bf2f(d4.z); v.w += bf2f(d4.w);
    }
    ((float4*)out)[i] = v;
}

extern "C" void kernel_launch(void* const* d_in, const int* in_sizes, int n_in,
                              void* d_out, int out_size, void* d_ws, size_t ws_size,
                              hipStream_t stream) {
    const float* x    = (const float*)d_in[0];
    const float* Wg   = (const float*)d_in[2];
    const float* bias = (const float*)d_in[3];
    const float* W1   = (const float*)d_in[4];
    const float* W3   = (const float*)d_in[5];
    const float* W2   = (const float*)d_in[6];
    const float* Wsg  = (const float*)d_in[7];
    const float* Wsu  = (const float*)d_in[8];
    const float* Wsd  = (const float*)d_in[9];
    float* out = (float*)d_out;
    char* ws = (char*)d_ws;

    size_t off = 0;
    auto carve = [&](size_t bytes) -> char* {
        char* p = ws + off;
        off = (off + bytes + 255) & ~(size_t)255;
        return p;
    };
    u16* x_bf   = (u16*)carve((size_t)T_ * H_ * 2);                 // 2 MB
    u16* gu_sh  = (u16*)carve((size_t)T_ * 2 * IS_ * 2);            // 4 MB
    u16* c1     = (u16*)carve((size_t)T_ * IS_ * 2);                // 2 MB
    u16* Wsht   = (u16*)carve((size_t)2 * IS_ * H_ * 2);            // 4 MB
    u16* dwn    = gu_sh;   // alias: 8 MB over gu_sh+c1+Wsht[0:2MB], all dead by then
    int* counts    = (int*)carve(E_ * sizeof(int));
    int* tok_list  = (int*)carve((size_t)E_ * T_ * 4);
    int* slot_list = (int*)carve((size_t)E_ * T_ * 4);
    float* wt_list = (float*)carve((size_t)E_ * T_ * 4);
    u16* W13t   = (u16*)carve((size_t)E_ * 2 * I_ * H_ * 2);        // 32 MB

    size_t remain = (ws_size > off) ? (ws_size - off) : 0;
    long cap = (long)(remain / ((size_t)E_ * 1024 * 2));
    if (cap > 768) cap = 768;
    cap = (cap / 128) * 128;
    if (cap < 128) cap = 128;
    u16* gu_e = (u16*)carve((size_t)E_ * cap * 1024 * 2);
    int capB = (int)(cap / 128);

    hipMemsetAsync(counts, 0, E_ * sizeof(int), stream);
    convert_kernel<<<T_ * H_ / 4 / 256, 256, 0, stream>>>(x, x_bf, T_ * H_ / 4);
    router_kernel<<<T_, 256, 0, stream>>>(x, Wg, bias, counts, tok_list, slot_list, wt_list, (int)cap);

    dim3 blk(256);
    // ---- shared experts: [Wsg^T ; Wsu^T] one GEMM N=2048 ----
    transpose2_bf16_kernel<<<dim3(IS_ / 64, H_ / 64, 2), blk, 0, stream>>>(
        Wsg, Wsu, Wsht, IS_, H_, 0, 0, 1, (long)IS_ * H_);
    gemm_bt_kernel<false, false, false, false><<<dim3(2 * IS_ / 128, T_ / 128, 1), blk, 0, stream>>>(
        x_bf, H_, 0, Wsht, H_, 0, (void*)gu_sh, 2 * IS_, 0, T_, H_, nullptr, 0, nullptr, nullptr);
    act_shared_kernel<<<T_ * IS_ / 4 / 256, 256, 0, stream>>>(gu_sh, c1, T_ * IS_ / 4);
    transpose2_bf16_kernel<<<dim3(H_ / 64, IS_ / 64, 1), blk, 0, stream>>>(
        Wsd, Wsd, Wsht, H_, IS_, 0, 0, 1, 0);
    gemm_bt_kernel<false, false, false, true><<<dim3(H_ / 128, T_ / 128, 1), blk, 0, stream>>>(
        c1, IS_, 0, Wsht, IS_, 0, (void*)out, H_, 0, T_, IS_, nullptr, 0, nullptr, nullptr);
    // ---- routed experts: [W1^T ; W3^T] per expert, one up-GEMM N=1024 ----
    transpose2_bf16_kernel<<<dim3(I_ / 64, H_ / 64, 2 * E_), blk, 0, stream>>>(
        W1, W3, W13t, I_, H_, (long)H_ * I_, (long)2 * I_ * H_, E_, (long)I_ * H_);
    gemm_bt_kernel<true, true, false, false><<<dim3(1024 / 128, capB, E_), blk, 0, stream>>>(
        x_bf, H_, 0, W13t, H_, (long)2 * I_ * H_, (void*)gu_e, 1024, (long)cap * 1024, 0, H_,
        counts, (int)cap, tok_list, nullptr);
    act_expert_kernel<<<dim3(E_, (unsigned)cap), 128, 0, stream>>>(gu_e, wt_list, counts, (int)cap);
    transpose2_bf16_kernel<<<dim3(H_ / 64, I_ / 64, E_), blk, 0, stream>>>(
        W2, W2, W13t, H_, I_, (long)I_ * H_, (long)H_ * I_, E_, 0);
    gemm_bt_kernel<true, false, true, false><<<dim3(H_ / 128, capB, E_), blk, 0, stream>>>(
        gu_e, 1024, (long)cap * 1024, W13t, I_, (long)H_ * I_, (void*)dwn, H_, 0, 0, I_,
        counts, (int)cap, nullptr, slot_list);
    final_add_kernel<<<T_ * H_ / 4 / 256, 256, 0, stream>>>(out, dwn);
}

// Round 5
// 142.067 us; speedup vs baseline: 2.2700x; 1.0769x over previous
//
#include <hip/hip_runtime.h>
#include <hip/hip_bf16.h>
#include <math.h>

#define T_ 1024
#define H_ 1024
#define E_ 16
#define I_ 512
#define KSEL 4
#define IS_ 1024

typedef unsigned short u16;
typedef __attribute__((ext_vector_type(8))) short short8;
typedef __attribute__((ext_vector_type(4))) float f32x4;

__device__ __forceinline__ u16 f2bf(float f) {
    union { float f; unsigned int u; } v; v.f = f;
    unsigned int u = v.u;
    return (u16)((u + 0x7fffu + ((u >> 16) & 1u)) >> 16);
}
__device__ __forceinline__ float bf2f(u16 b) {
    union { unsigned int u; float f; } v; v.u = ((unsigned int)b) << 16;
    return v.f;
}
__device__ __forceinline__ unsigned cvtpk(float lo, float hi) {
    unsigned r;
    asm("v_cvt_pk_bf16_f32 %0, %1, %2" : "=v"(r) : "v"(lo), "v"(hi));
    return r;   // bf16(lo) in [15:0], bf16(hi) in [31:16]
}

__device__ __forceinline__ void gload16(const u16* g, u16* l) {
    __builtin_amdgcn_global_load_lds(
        (const __attribute__((address_space(1))) void*)g,
        (__attribute__((address_space(3))) void*)l, 16, 0, 0);
}

// ---------------- x -> bf16 ----------------
__global__ void convert_kernel(const float* __restrict__ in, u16* __restrict__ out, int n4) {
    int i = blockIdx.x * blockDim.x + threadIdx.x;
    if (i >= n4) return;
    float4 v = ((const float4*)in)[i];
    ushort4 o;
    o.x = f2bf(v.x); o.y = f2bf(v.y); o.z = f2bf(v.z); o.w = f2bf(v.w);
    ((ushort4*)out)[i] = o;
}

// ---------------- router: 1 block/token, thread=(expert, H-chunk) ----------------
__global__ __launch_bounds__(256)
void router_kernel(const float* __restrict__ x, const float* __restrict__ Wg,
                   const float* __restrict__ bias, int* __restrict__ counts,
                   int* __restrict__ tok_list, int* __restrict__ slot_list,
                   float* __restrict__ wt_list, int cap) {
    __shared__ float part[4][16];
    int t = blockIdx.x;
    int tid = threadIdx.x;
    int e = tid & 15;
    int q = tid >> 4;   // 0..15, 64-element chunk
    const float4* xv = (const float4*)(x + (long)t * H_) + q * 16;
    const float4* wv = (const float4*)(Wg + (long)e * H_) + q * 16;
    float d = 0.f;
#pragma unroll
    for (int i = 0; i < 16; i++) {
        float4 a = xv[i], b = wv[i];
        d += a.x * b.x + a.y * b.y + a.z * b.z + a.w * b.w;
    }
    d += __shfl_down(d, 16);
    d += __shfl_down(d, 32);
    if ((tid & 63) < 16) part[tid >> 6][e] = d;
    __syncthreads();
    if (tid >= 64) return;
    int lane = tid;
    float lg = part[0][e] + part[1][e] + part[2][e] + part[3][e];
    float sp = fmaxf(lg, 0.f) + log1pf(expf(-fabsf(lg)));  // stable softplus
    float s = sqrtf(sp);
    float bs = s + bias[e];
    int sel[KSEL]; float ssel[KSEL]; float wsum = 0.f;
#pragma unroll
    for (int k = 0; k < KSEL; k++) {
        float mv = bs; int me = e;
#pragma unroll
        for (int off = 1; off < 16; off <<= 1) {
            float ov = __shfl_xor(mv, off);
            int oe = __shfl_xor(me, off);
            if (ov > mv || (ov == mv && oe < me)) { mv = ov; me = oe; }
        }
        sel[k] = me;
        float sk = __shfl(s, (lane & 48) | me);
        ssel[k] = sk; wsum += sk;
        if (e == me) bs = -1e30f;
    }
    float inv = 2.5f / wsum;
    if (lane < KSEL) {
        int k = lane;
        int se = sel[k];
        int pos = atomicAdd(&counts[se], 1);
        if (pos < cap) {
            tok_list[se * T_ + pos] = t;
            slot_list[se * T_ + pos] = t * KSEL + k;
            wt_list[se * T_ + pos] = ssel[k] * inv;
        }
    }
}

// ------- pipelined bf16 GEMM, B read directly as fp32 [K][N] (converted inline) ----
// C[M,N] = A[M,K](bf16) * B[K,N](fp32); B dual-source: col n<nsplit from B0, else B1.
template<bool EXPERT, bool GATHER_A, bool SCATTER_C, bool C_F32>
__global__ __launch_bounds__(256)
void gemm_bf32_kernel(const u16* __restrict__ A, int lda, long sAe,
                      const float* __restrict__ B0, const float* __restrict__ B1,
                      int nsplit, int ldb, long sBe,
                      void* __restrict__ C, int ldc, long sCe,
                      int Mfull, int Ktot,
                      const int* __restrict__ counts, int cap,
                      const int* __restrict__ gather, const int* __restrict__ scatter) {
    int e = 0, Mlim = Mfull;
    if (EXPERT) { e = blockIdx.z; int c = counts[e]; Mlim = c < cap ? c : cap; }
    int mbase = blockIdx.y * 128;
    if (mbase >= Mlim) return;
    int nbase = blockIdx.x * 128;

    __shared__ __align__(16) u16 As[2][128 * 64];
    __shared__ __align__(16) u16 Bs[2][128 * 64];

    int tid = threadIdx.x;
    int lane = tid & 63, wid = tid >> 6;

    // ---- A staging (global_load_lds, pre-swizzled source, key R&7) ----
    int srow = tid >> 3;
    int sc = tid & 7;
    int ssrc = ((sc ^ (srow & 7)) << 3);
    const u16* Ab = A + ((EXPERT && !GATHER_A) ? (long)e * sAe : 0L);
    const u16* aptr[4];
#pragma unroll
    for (int j = 0; j < 4; j++) {
        int gr = mbase + j * 32 + srow;
        int grc = gr < Mlim ? gr : (Mlim - 1);
        long ar = GATHER_A ? (long)gather[e * T_ + grc] : (long)grc;
        aptr[j] = Ab + ar * (long)lda + ssrc;
    }
    u16* asb = &As[0][0];
    u16* adst = asb + tid * 8;

    // ---- B staging (reg-staged fp32 -> bf16 transpose, key (n>>2)&7) ----
    int ng = tid & 31;       // n-group: cols ng*4 .. ng*4+3
    int kg2 = tid >> 5;      // k-groups kg2 and kg2+8 (k = kg*4)
    const float* Bb = (nbase < nsplit) ? (B0 + nbase) : (B1 + (nbase - nsplit));
    if (EXPERT) Bb += (long)e * sBe;
    Bb += ng * 4;
    f32x4 breg[2][4];

    int wm = wid >> 1, wn = wid & 1;
    int lr = lane & 15, lk = lane >> 4;
    f32x4 acc[4][4] = {};

    int nt = Ktot >> 6;

    // prologue: tile 0
#pragma unroll
    for (int m = 0; m < 2; m++)
#pragma unroll
        for (int i = 0; i < 4; i++)
            breg[m][i] = *(const f32x4*)(Bb + (long)((kg2 + m * 8) * 4 + i) * ldb);
#pragma unroll
    for (int j = 0; j < 4; j++) gload16(aptr[j], adst + j * 2048);
    {
        u16* bsw = &Bs[0][0];
#pragma unroll
        for (int m = 0; m < 2; m++) {
            int kg = kg2 + m * 8;
            int c0 = kg >> 1, hf = (kg & 1) * 4;
            int c = c0 ^ (ng & 7);
#pragma unroll
            for (int j = 0; j < 4; j++) {
                int n = ng * 4 + j;
                uint2 v;
                v.x = cvtpk(breg[m][0][j], breg[m][1][j]);
                v.y = cvtpk(breg[m][2][j], breg[m][3][j]);
                *(uint2*)&bsw[n * 64 + c * 8 + hf] = v;
            }
        }
    }
    __syncthreads();

    for (int t = 0; t < nt; t++) {
        int cur = t & 1, nxt = cur ^ 1;
        bool pf = (t + 1 < nt);
        if (pf) {
            int k0 = (t + 1) << 6;
#pragma unroll
            for (int m = 0; m < 2; m++)
#pragma unroll
                for (int i = 0; i < 4; i++)
                    breg[m][i] = *(const f32x4*)(Bb + (long)(k0 + (kg2 + m * 8) * 4 + i) * ldb);
#pragma unroll
            for (int j = 0; j < 4; j++)
                gload16(aptr[j] + k0, adst + nxt * 8192 + j * 2048);
        }
        const u16* Asc = &As[cur][0];
        const u16* Bsc = &Bs[cur][0];
#pragma unroll
        for (int kk = 0; kk < 2; kk++) {
            short8 afr[4], bfr[4];
#pragma unroll
            for (int mi = 0; mi < 4; mi++) {
                int R = wm * 64 + mi * 16 + lr;
                afr[mi] = *(const short8*)&Asc[R * 64 + ((((kk << 2) + lk) ^ (R & 7)) << 3)];
            }
#pragma unroll
            for (int ni = 0; ni < 4; ni++) {
                int R = wn * 64 + ni * 16 + lr;
                bfr[ni] = *(const short8*)&Bsc[R * 64 + ((((kk << 2) + lk) ^ ((R >> 2) & 7)) << 3)];
            }
#pragma unroll
            for (int mi = 0; mi < 4; mi++)
#pragma unroll
                for (int ni = 0; ni < 4; ni++)
                    acc[mi][ni] = __builtin_amdgcn_mfma_f32_16x16x32_bf16(afr[mi], bfr[ni], acc[mi][ni], 0, 0, 0);
        }
        if (pf) {
            u16* bsw = &Bs[nxt][0];
#pragma unroll
            for (int m = 0; m < 2; m++) {
                int kg = kg2 + m * 8;
                int c0 = kg >> 1, hf = (kg & 1) * 4;
                int c = c0 ^ (ng & 7);
#pragma unroll
                for (int j = 0; j < 4; j++) {
                    int n = ng * 4 + j;
                    uint2 v;
                    v.x = cvtpk(breg[m][0][j], breg[m][1][j]);
                    v.y = cvtpk(breg[m][2][j], breg[m][3][j]);
                    *(uint2*)&bsw[n * 64 + c * 8 + hf] = v;
                }
            }
        }
        __syncthreads();
    }

    // epilogue: C/D layout col = lane&15, row = (lane>>4)*4 + reg
    u16* Cb = (u16*)C;
    float* Cf = (float*)C;
    long cbase = (EXPERT && !SCATTER_C) ? (long)e * sCe : 0L;
#pragma unroll
    for (int mi = 0; mi < 4; mi++) {
#pragma unroll
        for (int j = 0; j < 4; j++) {
            int rowt = wm * 64 + mi * 16 + lk * 4 + j;
            int gr = mbase + rowt;
            if (gr >= Mlim) continue;
            long crow = SCATTER_C ? (long)scatter[e * T_ + gr] : (long)gr;
            long rb = cbase + crow * (long)ldc;
#pragma unroll
            for (int ni = 0; ni < 4; ni++) {
                int col = nbase + wn * 64 + ni * 16 + lr;
                float v = acc[mi][ni][j];
                if (C_F32) Cf[rb + col] = v;
                else       Cb[rb + col] = f2bf(v);
            }
        }
    }
}

// ---------------- shared act: c1 = silu(g) * u, gu layout [t][g(1024) | u(1024)] ----
__global__ void act_shared_kernel(const u16* __restrict__ gu, u16* __restrict__ c1, int n4) {
    int i = blockIdx.x * blockDim.x + threadIdx.x;
    if (i >= n4) return;
    int t = (i << 2) >> 10;
    int o = (i << 2) & 1023;
    ushort4 g4 = *(const ushort4*)&gu[(long)t * 2048 + o];
    ushort4 u4 = *(const ushort4*)&gu[(long)t * 2048 + 1024 + o];
    ushort4 r;
    float g, u;
    g = bf2f(g4.x); u = bf2f(u4.x); r.x = f2bf(g / (1.f + expf(-g)) * u);
    g = bf2f(g4.y); u = bf2f(u4.y); r.y = f2bf(g / (1.f + expf(-g)) * u);
    g = bf2f(g4.z); u = bf2f(u4.z); r.z = f2bf(g / (1.f + expf(-g)) * u);
    g = bf2f(g4.w); u = bf2f(u4.w); r.w = f2bf(g / (1.f + expf(-g)) * u);
    *(ushort4*)&c1[(long)(i << 2)] = r;
}

// ---------------- routed act: clamped swiglu * weight, in-place over g half --------
__global__ void act_expert_kernel(u16* __restrict__ gu, const float* __restrict__ wt_list,
                                  const int* __restrict__ counts, int cap) {
    int e = blockIdx.x, pos = blockIdx.y;
    int c = counts[e]; if (c > cap) c = cap;
    if (pos >= c) return;
    float w = wt_list[e * T_ + pos];
    long base = ((long)e * cap + pos) * 1024;
    int o = threadIdx.x * 4;
    ushort4 g4 = *(const ushort4*)&gu[base + o];
    ushort4 u4 = *(const ushort4*)&gu[base + 512 + o];
    ushort4 r;
    float g, u;
    g = fminf(bf2f(g4.x), 7.f); u = fminf(fmaxf(bf2f(u4.x), -7.f), 7.f);
    r.x = f2bf(g / (1.f + expf(-1.702f * g)) * (u + 1.f) * w);
    g = fminf(bf2f(g4.y), 7.f); u = fminf(fmaxf(bf2f(u4.y), -7.f), 7.f);
    r.y = f2bf(g / (1.f + expf(-1.702f * g)) * (u + 1.f) * w);
    g = fminf(bf2f(g4.z), 7.f); u = fminf(fmaxf(bf2f(u4.z), -7.f), 7.f);
    r.z = f2bf(g / (1.f + expf(-1.702f * g)) * (u + 1.f) * w);
    g = fminf(bf2f(g4.w), 7.f); u = fminf(fmaxf(bf2f(u4.w), -7.f), 7.f);
    r.w = f2bf(g / (1.f + expf(-1.702f * g)) * (u + 1.f) * w);
    *(ushort4*)&gu[base + o] = r;
}

// ---------------- final: out += sum_k routed(t,k) ----------------
__global__ void final_add_kernel(float* __restrict__ out, const u16* __restrict__ down) {
    int i = blockIdx.x * blockDim.x + threadIdx.x;
    int o = i * 4;
    int t = o >> 10;
    int h = o & (H_ - 1);
    float4 v = ((float4*)out)[i];
#pragma unroll
    for (int k = 0; k < KSEL; k++) {
        const u16* dr = down + ((long)(t * KSEL + k) << 10) + h;
        ushort4 d4 = *(const ushort4*)dr;
        v.x += bf2f(d4.x); v.y += bf2f(d4.y); v.z += bf2f(d4.z); v.w += bf2f(d4.w);
    }
    ((float4*)out)[i] = v;
}

extern "C" void kernel_launch(void* const* d_in, const int* in_sizes, int n_in,
                              void* d_out, int out_size, void* d_ws, size_t ws_size,
                              hipStream_t stream) {
    const float* x    = (const float*)d_in[0];
    const float* Wg   = (const float*)d_in[2];
    const float* bias = (const float*)d_in[3];
    const float* W1   = (const float*)d_in[4];
    const float* W3   = (const float*)d_in[5];
    const float* W2   = (const float*)d_in[6];
    const float* Wsg  = (const float*)d_in[7];
    const float* Wsu  = (const float*)d_in[8];
    const float* Wsd  = (const float*)d_in[9];
    float* out = (float*)d_out;
    char* ws = (char*)d_ws;

    size_t off = 0;
    auto carve = [&](size_t bytes) -> char* {
        char* p = ws + off;
        off = (off + bytes + 255) & ~(size_t)255;
        return p;
    };
    u16* x_bf   = (u16*)carve((size_t)T_ * H_ * 2);                 // 2 MB
    u16* gu_sh  = (u16*)carve((size_t)T_ * 2 * IS_ * 2);            // 4 MB
    u16* c1     = (u16*)carve((size_t)T_ * IS_ * 2);                // 2 MB
    u16* dwn    = (u16*)carve((size_t)T_ * KSEL * H_ * 2);          // 8 MB
    int* counts    = (int*)carve(E_ * sizeof(int));
    int* tok_list  = (int*)carve((size_t)E_ * T_ * 4);
    int* slot_list = (int*)carve((size_t)E_ * T_ * 4);
    float* wt_list = (float*)carve((size_t)E_ * T_ * 4);

    size_t remain = (ws_size > off) ? (ws_size - off) : 0;
    long cap = (long)(remain / ((size_t)E_ * 1024 * 2));
    if (cap > 768) cap = 768;
    cap = (cap / 128) * 128;
    if (cap < 128) cap = 128;
    u16* gu_e = (u16*)carve((size_t)E_ * cap * 1024 * 2);
    int capB = (int)(cap / 128);

    hipMemsetAsync(counts, 0, E_ * sizeof(int), stream);
    convert_kernel<<<T_ * H_ / 4 / 256, 256, 0, stream>>>(x, x_bf, T_ * H_ / 4);
    router_kernel<<<T_, 256, 0, stream>>>(x, Wg, bias, counts, tok_list, slot_list, wt_list, (int)cap);

    dim3 blk(256);
    // ---- shared experts: up GEMM N=2048 (Wsg cols | Wsu cols), B fp32 direct ----
    gemm_bf32_kernel<false, false, false, false><<<dim3(2 * IS_ / 128, T_ / 128, 1), blk, 0, stream>>>(
        x_bf, H_, 0, Wsg, Wsu, IS_, IS_, 0,
        (void*)gu_sh, 2 * IS_, 0, T_, H_, nullptr, 0, nullptr, nullptr);
    act_shared_kernel<<<T_ * IS_ / 4 / 256, 256, 0, stream>>>(gu_sh, c1, T_ * IS_ / 4);
    // ---- shared down: B = Wsd [IS][H] fp32 direct -> out fp32 ----
    gemm_bf32_kernel<false, false, false, true><<<dim3(H_ / 128, T_ / 128, 1), blk, 0, stream>>>(
        c1, IS_, 0, Wsd, Wsd, H_, H_, 0,
        (void*)out, H_, 0, T_, IS_, nullptr, 0, nullptr, nullptr);
    // ---- routed experts: up GEMM N=1024 (W1 cols | W3 cols), gathered A ----
    gemm_bf32_kernel<true, true, false, false><<<dim3(1024 / 128, capB, E_), blk, 0, stream>>>(
        x_bf, H_, 0, W1, W3, I_, I_, (long)H_ * I_,
        (void*)gu_e, 1024, (long)cap * 1024, 0, H_,
        counts, (int)cap, tok_list, nullptr);
    act_expert_kernel<<<dim3(E_, (unsigned)cap), 128, 0, stream>>>(gu_e, wt_list, counts, (int)cap);
    // ---- routed experts: down GEMM, B = W2 [e][I][H] fp32 direct, scatter C ----
    gemm_bf32_kernel<true, false, true, false><<<dim3(H_ / 128, capB, E_), blk, 0, stream>>>(
        gu_e, 1024, (long)cap * 1024, W2, W2, H_, H_, (long)I_ * H_,
        (void*)dwn, H_, 0, 0, I_,
        counts, (int)cap, nullptr, slot_list);
    final_add_kernel<<<T_ * H_ / 4 / 256, 256, 0, stream>>>(out, dwn);
}